// Round 1
// baseline (222.254 us; speedup 1.0000x reference)
//
#include <hip/hip_runtime.h>
#include <hip/hip_bf16.h>

typedef __hip_bfloat16 bf16;
typedef __attribute__((ext_vector_type(4))) float f32x4;
typedef __attribute__((ext_vector_type(8))) short bf16x8;  // 8 bf16 in 4 VGPRs

// ---------------------------------------------------------------------------
// helpers
// ---------------------------------------------------------------------------
__device__ __forceinline__ void gload_lds16(const bf16* g, bf16* l) {
  __builtin_amdgcn_global_load_lds(
      (const __attribute__((address_space(1))) unsigned int*)(const void*)g,
      (__attribute__((address_space(3))) unsigned int*)(void*)l,
      16, 0, 0);
}

// ---------------------------------------------------------------------------
// fp32 -> bf16 conversion (vectorized, exact grid)
// ---------------------------------------------------------------------------
__global__ void cvt_f32_bf16(const float* __restrict__ in, bf16* __restrict__ out) {
  size_t i = ((size_t)blockIdx.x * 256 + threadIdx.x) * 4;
  float4 v = *reinterpret_cast<const float4*>(in + i);
  bf16 o[4] = {__float2bfloat16(v.x), __float2bfloat16(v.y),
               __float2bfloat16(v.z), __float2bfloat16(v.w)};
  *reinterpret_cast<ushort4*>(out + i) = *reinterpret_cast<const ushort4*>(o);
}

// ---------------------------------------------------------------------------
// addend[w][h][row][col64] = masked ? mask : table[pos_idx, h] ; col>=49 -> -1e30
// handles pos_idx stored as int32 OR int64 (odd-word-zero probe)
// ---------------------------------------------------------------------------
__global__ void build_addend(const float* __restrict__ mask, const int* __restrict__ pos,
                             const float* __restrict__ table, float* __restrict__ out) {
  int idx = blockIdx.x * 256 + threadIdx.x;   // total 64*12*49*64 = 2,408,448
  int col = idx & 63;
  int rh  = idx >> 6;
  int row = rh % 49;
  int h   = (rh / 49) % 12;
  int w   = rh / (49 * 12);
  float v = -1e30f;
  if (col < 49) {
    float m = mask[(w * 49 + row) * 49 + col];
    if (m != 0.0f) {
      v = m;
    } else {
      bool is64 = (pos[1] == 0) & (pos[3] == 0) & (pos[5] == 0) & (pos[7] == 0) &
                  (pos[9] == 0) & (pos[11] == 0) & (pos[13] == 0) & (pos[15] == 0);
      int pi = (w * 49 + row) * 49 + col;
      int p = is64 ? pos[2 * pi] : pos[pi];
      v = table[p * 12 + h];
    }
  }
  out[idx] = v;
}

// ---------------------------------------------------------------------------
// GEMM: C[M,N] = A[M,K] @ B[N,K]^T + bias[N]   (A,B bf16 row-major K-contig)
// 128x128 tile, BK=32, 4 waves (2x2 of 64x64), global_load_lds width 16.
// M%128==0, N%128==0, K%32==0 guaranteed by caller.
// ---------------------------------------------------------------------------
template <bool OUT_BF16>
__global__ __launch_bounds__(256) void gemm_bt(
    const bf16* __restrict__ A, const bf16* __restrict__ Bm,
    const float* __restrict__ bias, void* __restrict__ Cout,
    int M, int N, int K, int nbn) {
  __shared__ bf16 As[128 * 32];
  __shared__ bf16 Bs[128 * 32];
  const int t = threadIdx.x;
  const int lane = t & 63;
  const int w = t >> 6, wr = w >> 1, wc = w & 1;
  const int bm = blockIdx.x / nbn, bn = blockIdx.x % nbn;
  const int lr = lane & 15, lg = lane >> 4;

  const bf16* ag = A + ((size_t)(bm * 128 + (t >> 2))) * K + (t & 3) * 8;
  const bf16* bg = Bm + ((size_t)(bn * 128 + (t >> 2))) * K + (t & 3) * 8;
  bf16* al = As + t * 8;
  bf16* bl = Bs + t * 8;
  const size_t rstep = (size_t)64 * K;

  f32x4 acc[4][4] = {};

  for (int k0 = 0; k0 < K; k0 += 32) {
    gload_lds16(ag + k0, al);
    gload_lds16(ag + k0 + rstep, al + 64 * 32);
    gload_lds16(bg + k0, bl);
    gload_lds16(bg + k0 + rstep, bl + 64 * 32);
    __syncthreads();
    bf16x8 af[4], bff[4];
    const bf16* ab = As + (wr * 64 + lr) * 32 + lg * 8;
    const bf16* bb = Bs + (wc * 64 + lr) * 32 + lg * 8;
#pragma unroll
    for (int i = 0; i < 4; i++) af[i] = *reinterpret_cast<const bf16x8*>(ab + i * 16 * 32);
#pragma unroll
    for (int j = 0; j < 4; j++) bff[j] = *reinterpret_cast<const bf16x8*>(bb + j * 16 * 32);
#pragma unroll
    for (int i = 0; i < 4; i++)
#pragma unroll
      for (int j = 0; j < 4; j++)
        acc[i][j] = __builtin_amdgcn_mfma_f32_16x16x32_bf16(af[i], bff[j], acc[i][j], 0, 0, 0);
    __syncthreads();
  }

#pragma unroll
  for (int i = 0; i < 4; i++) {
    int row0 = bm * 128 + wr * 64 + i * 16 + lg * 4;
#pragma unroll
    for (int j = 0; j < 4; j++) {
      int col = bn * 128 + wc * 64 + j * 16 + lr;
      float bv = bias[col];
#pragma unroll
      for (int r = 0; r < 4; r++) {
        float v = acc[i][j][r] + bv;
        if (OUT_BF16)
          ((bf16*)Cout)[(size_t)(row0 + r) * N + col] = __float2bfloat16(v);
        else
          ((float*)Cout)[(size_t)(row0 + r) * N + col] = v;
      }
    }
  }
}

// ---------------------------------------------------------------------------
// fused window attention: 1 wave per (b_, h). 49x49 scores padded to 64x64.
// qkv layout: [50176][1152] bf16, cols [0,384)=Q, [384,768)=K, [768,1152)=V.
// ---------------------------------------------------------------------------
__global__ __launch_bounds__(64) void attn_kernel(
    const bf16* __restrict__ qkv, const float* __restrict__ addend,
    bf16* __restrict__ attn_out) {
  const int bid = blockIdx.x;   // 0..12287
  const int b = bid / 12;
  const int h = bid % 12;
  const int w = b & 63;
  const int lane = threadIdx.x;
  const int lr = lane & 15, lg = lane >> 4;
  const float scale = 0.17677669529663687f;  // 32^-0.5

  __shared__ ushort p_lds[64][72];
  __shared__ ushort vT[32][72];

  const size_t base = (size_t)b * 49 * 1152;

  // --- Q, K fragments straight from global (rows >= 49 clamped to 48)
  bf16x8 qf[4], kf[4];
#pragma unroll
  for (int i = 0; i < 4; i++) {
    int rw = i * 16 + lr;
    int row = rw < 49 ? rw : 48;
    qf[i] = *reinterpret_cast<const bf16x8*>(qkv + base + (size_t)row * 1152 + h * 32 + lg * 8);
    kf[i] = *reinterpret_cast<const bf16x8*>(qkv + base + (size_t)row * 1152 + 384 + h * 32 + lg * 8);
  }

  // --- stage V transposed into LDS: vT[d][k] = V[k][d]; pad k>=49 with 0
  if (lane < 49) {
#pragma unroll
    for (int c4 = 0; c4 < 4; c4++) {
      bf16x8 vv = *reinterpret_cast<const bf16x8*>(
          qkv + base + (size_t)lane * 1152 + 768 + h * 32 + c4 * 8);
#pragma unroll
      for (int cc = 0; cc < 8; cc++) vT[c4 * 8 + cc][lane] = (ushort)vv[cc];
    }
  } else {
#pragma unroll
    for (int c = 0; c < 32; c++) vT[c][lane] = 0;
  }

  // --- S = Q @ K^T (64x64 padded), C-layout: row=(lg*4+reg), col=lr per tile
  f32x4 acc[4][4] = {};
#pragma unroll
  for (int i = 0; i < 4; i++)
#pragma unroll
    for (int j = 0; j < 4; j++)
      acc[i][j] = __builtin_amdgcn_mfma_f32_16x16x32_bf16(qf[i], kf[j], acc[i][j], 0, 0, 0);

  // --- softmax in-register (rows distributed: 16 lanes of group lg share rows)
  const float* add_base = addend + (size_t)(w * 12 + h) * 49 * 64;
  float rowscale[4][4];
#pragma unroll
  for (int i = 0; i < 4; i++) {
#pragma unroll
    for (int r = 0; r < 4; r++) {
      int row = i * 16 + lg * 4 + r;
      int rowc = row < 49 ? row : 48;
      float lv[4];
      float mx = -1e38f;
#pragma unroll
      for (int j = 0; j < 4; j++) {
        int col = j * 16 + lr;
        float ad = add_base[rowc * 64 + col];
        lv[j] = acc[i][j][r] * scale + ad;
        mx = fmaxf(mx, lv[j]);
      }
#pragma unroll
      for (int d = 1; d < 16; d <<= 1) mx = fmaxf(mx, __shfl_xor(mx, d, 64));
      float sum = 0.f;
#pragma unroll
      for (int j = 0; j < 4; j++) {
        lv[j] = __expf(lv[j] - mx);
        sum += lv[j];
      }
#pragma unroll
      for (int d = 1; d < 16; d <<= 1) sum += __shfl_xor(sum, d, 64);
      rowscale[i][r] = 1.0f / sum;
#pragma unroll
      for (int j = 0; j < 4; j++) acc[i][j][r] = lv[j];
    }
  }

  // --- write P (unnormalized) to LDS as bf16
#pragma unroll
  for (int i = 0; i < 4; i++)
#pragma unroll
    for (int j = 0; j < 4; j++)
#pragma unroll
      for (int r = 0; r < 4; r++) {
        int row = i * 16 + lg * 4 + r;
        int col = j * 16 + lr;
        p_lds[row][col] = __bfloat16_as_ushort(__float2bfloat16(acc[i][j][r]));
      }
  __syncthreads();

  // --- O = P @ V  (K-dim 64, 2 steps of 32)
  f32x4 acc2[4][2] = {};
#pragma unroll
  for (int ks = 0; ks < 2; ks++) {
    bf16x8 vf[2];
#pragma unroll
    for (int dt = 0; dt < 2; dt++)
      vf[dt] = *reinterpret_cast<const bf16x8*>(&vT[dt * 16 + lr][ks * 32 + lg * 8]);
#pragma unroll
    for (int i = 0; i < 4; i++) {
      bf16x8 pf = *reinterpret_cast<const bf16x8*>(&p_lds[i * 16 + lr][ks * 32 + lg * 8]);
#pragma unroll
      for (int dt = 0; dt < 2; dt++)
        acc2[i][dt] = __builtin_amdgcn_mfma_f32_16x16x32_bf16(pf, vf[dt], acc2[i][dt], 0, 0, 0);
    }
  }

  // --- store attn_out (bf16), normalize by 1/rowsum
#pragma unroll
  for (int i = 0; i < 4; i++)
#pragma unroll
    for (int r = 0; r < 4; r++) {
      int row = i * 16 + lg * 4 + r;
      if (row < 49) {
        float rs = rowscale[i][r];
#pragma unroll
        for (int dt = 0; dt < 2; dt++) {
          int col = h * 32 + dt * 16 + lr;
          attn_out[((size_t)b * 49 + row) * 384 + col] =
              __float2bfloat16(acc2[i][dt][r] * rs);
        }
      }
    }
}

// ---------------------------------------------------------------------------
// launch
// ---------------------------------------------------------------------------
extern "C" void kernel_launch(void* const* d_in, const int* in_sizes, int n_in,
                              void* d_out, int out_size, void* d_ws, size_t ws_size,
                              hipStream_t stream) {
  const float* x      = (const float*)d_in[0];
  const float* mask   = (const float*)d_in[1];
  const int*   posidx = (const int*)d_in[2];
  const float* table  = (const float*)d_in[3];
  const float* w_qkv  = (const float*)d_in[4];
  const float* b_qkv  = (const float*)d_in[5];
  const float* w_proj = (const float*)d_in[6];
  const float* b_proj = (const float*)d_in[7];
  float* out = (float*)d_out;

  char* ws = (char*)d_ws;
  bf16*  xb     = (bf16*)(ws + 0);            // 50176*384   bf16 = 38,535,168 B
  bf16*  wqkvb  = (bf16*)(ws + 38535168);     // 1152*384    bf16 =    884,736 B
  bf16*  wprojb = (bf16*)(ws + 39419904);     // 384*384     bf16 =    294,912 B
  bf16*  qkv    = (bf16*)(ws + 39714816);     // 50176*1152  bf16 = 115,605,504 B
  bf16*  aout   = (bf16*)(ws + 155320320);    // 50176*384   bf16 = 38,535,168 B
  float* addend = (float*)(ws + 193855488);   // 64*12*49*64 f32  =  9,633,792 B

  // conversions (exact grids: sizes all divisible by 1024)
  cvt_f32_bf16<<<18816, 256, 0, stream>>>(x, xb);        // 19,267,584 elems
  cvt_f32_bf16<<<432, 256, 0, stream>>>(w_qkv, wqkvb);   //    442,368 elems
  cvt_f32_bf16<<<144, 256, 0, stream>>>(w_proj, wprojb); //    147,456 elems

  // fused bias+mask addend table
  build_addend<<<9408, 256, 0, stream>>>(mask, posidx, table, addend);

  // qkv = x @ w_qkv^T + b_qkv   (M=50176, N=1152, K=384)
  gemm_bt<true><<<392 * 9, 256, 0, stream>>>(xb, wqkvb, b_qkv, qkv, 50176, 1152, 384, 9);

  // attention per (window-batch, head)
  attn_kernel<<<12288, 64, 0, stream>>>(qkv, addend, aout);

  // out = attn_out @ w_proj^T + b_proj   (M=50176, N=384, K=384)
  gemm_bt<false><<<392 * 3, 256, 0, stream>>>(aout, wprojb, b_proj, out, 50176, 384, 384, 3);
}

// Round 2
// 198.427 us; speedup vs baseline: 1.1201x; 1.1201x over previous
//
#include <hip/hip_runtime.h>
#include <hip/hip_bf16.h>

typedef __hip_bfloat16 bf16;
typedef __attribute__((ext_vector_type(4))) float f32x4;
typedef __attribute__((ext_vector_type(8))) short bf16x8;  // 8 bf16 in 4 VGPRs

// ---------------------------------------------------------------------------
// helpers
// ---------------------------------------------------------------------------
__device__ __forceinline__ void gload_lds16(const bf16* g, bf16* l) {
  __builtin_amdgcn_global_load_lds(
      (const __attribute__((address_space(1))) unsigned int*)(const void*)g,
      (__attribute__((address_space(3))) unsigned int*)(void*)l,
      16, 0, 0);
}

// XCD-contiguous bijective swizzle; REQUIRES nwg % 8 == 0.
// HW dispatch maps orig -> XCD (orig % 8); this makes each XCD process a
// contiguous chunk of the logical grid so shared panels stay in one L2.
__device__ __forceinline__ int xcd_swz(int orig, int nwg) {
  return (orig & 7) * (nwg >> 3) + (orig >> 3);
}

// ---------------------------------------------------------------------------
// fp32 -> bf16 conversion (vectorized, exact grid)
// ---------------------------------------------------------------------------
__global__ void cvt_f32_bf16(const float* __restrict__ in, bf16* __restrict__ out) {
  size_t i = ((size_t)blockIdx.x * 256 + threadIdx.x) * 4;
  float4 v = *reinterpret_cast<const float4*>(in + i);
  bf16 o[4] = {__float2bfloat16(v.x), __float2bfloat16(v.y),
               __float2bfloat16(v.z), __float2bfloat16(v.w)};
  *reinterpret_cast<ushort4*>(out + i) = *reinterpret_cast<const ushort4*>(o);
}

// ---------------------------------------------------------------------------
// addend[w][h][row][col64] = masked ? mask : table[pos_idx, h] ; col>=49 -> -1e30
// handles pos_idx stored as int32 OR int64 (odd-word-zero probe)
// ---------------------------------------------------------------------------
__global__ void build_addend(const float* __restrict__ mask, const int* __restrict__ pos,
                             const float* __restrict__ table, float* __restrict__ out) {
  int idx = blockIdx.x * 256 + threadIdx.x;   // total 64*12*49*64 = 2,408,448
  int col = idx & 63;
  int rh  = idx >> 6;
  int row = rh % 49;
  int h   = (rh / 49) % 12;
  int w   = rh / (49 * 12);
  float v = -1e30f;
  if (col < 49) {
    float m = mask[(w * 49 + row) * 49 + col];
    if (m != 0.0f) {
      v = m;
    } else {
      bool is64 = (pos[1] == 0) & (pos[3] == 0) & (pos[5] == 0) & (pos[7] == 0) &
                  (pos[9] == 0) & (pos[11] == 0) & (pos[13] == 0) & (pos[15] == 0);
      int pi = (w * 49 + row) * 49 + col;
      int p = is64 ? pos[2 * pi] : pos[pi];
      v = table[p * 12 + h];
    }
  }
  out[idx] = v;
}

// ---------------------------------------------------------------------------
// GEMM: C[M,N] = A[M,K] @ B[N,K]^T + bias[N]   (A,B bf16 row-major K-contig)
// 128x128 tile, BK=32, 4 waves (2x2 of 64x64), global_load_lds width 16.
// M%128==0, N%128==0, K%32==0, grid%8==0 guaranteed by caller.
// ---------------------------------------------------------------------------
template <bool OUT_BF16>
__global__ __launch_bounds__(256) void gemm_bt(
    const bf16* __restrict__ A, const bf16* __restrict__ Bm,
    const float* __restrict__ bias, void* __restrict__ Cout,
    int M, int N, int K, int nbn, int nwg) {
  __shared__ bf16 As[128 * 32];
  __shared__ bf16 Bs[128 * 32];
  const int t = threadIdx.x;
  const int lane = t & 63;
  const int w = t >> 6, wr = w >> 1, wc = w & 1;
  const int lid = xcd_swz(blockIdx.x, nwg);
  const int bm = lid / nbn, bn = lid % nbn;
  const int lr = lane & 15, lg = lane >> 4;

  const bf16* ag = A + ((size_t)(bm * 128 + (t >> 2))) * K + (t & 3) * 8;
  const bf16* bg = Bm + ((size_t)(bn * 128 + (t >> 2))) * K + (t & 3) * 8;
  bf16* al = As + t * 8;
  bf16* bl = Bs + t * 8;
  const size_t rstep = (size_t)64 * K;

  f32x4 acc[4][4] = {};

  for (int k0 = 0; k0 < K; k0 += 32) {
    gload_lds16(ag + k0, al);
    gload_lds16(ag + k0 + rstep, al + 64 * 32);
    gload_lds16(bg + k0, bl);
    gload_lds16(bg + k0 + rstep, bl + 64 * 32);
    __syncthreads();
    bf16x8 af[4], bff[4];
    const bf16* ab = As + (wr * 64 + lr) * 32 + lg * 8;
    const bf16* bb = Bs + (wc * 64 + lr) * 32 + lg * 8;
#pragma unroll
    for (int i = 0; i < 4; i++) af[i] = *reinterpret_cast<const bf16x8*>(ab + i * 16 * 32);
#pragma unroll
    for (int j = 0; j < 4; j++) bff[j] = *reinterpret_cast<const bf16x8*>(bb + j * 16 * 32);
#pragma unroll
    for (int i = 0; i < 4; i++)
#pragma unroll
      for (int j = 0; j < 4; j++)
        acc[i][j] = __builtin_amdgcn_mfma_f32_16x16x32_bf16(af[i], bff[j], acc[i][j], 0, 0, 0);
    __syncthreads();
  }

#pragma unroll
  for (int i = 0; i < 4; i++) {
    int row0 = bm * 128 + wr * 64 + i * 16 + lg * 4;
#pragma unroll
    for (int j = 0; j < 4; j++) {
      int col = bn * 128 + wc * 64 + j * 16 + lr;
      float bv = bias[col];
#pragma unroll
      for (int r = 0; r < 4; r++) {
        float v = acc[i][j][r] + bv;
        if (OUT_BF16)
          ((bf16*)Cout)[(size_t)(row0 + r) * N + col] = __float2bfloat16(v);
        else
          ((float*)Cout)[(size_t)(row0 + r) * N + col] = v;
      }
    }
  }
}

// ---------------------------------------------------------------------------
// fused window attention: 1 wave per (b_, h). 49x49 scores padded to 64x64.
// qkv layout: [50176][1152] bf16, cols [0,384)=Q, [384,768)=K, [768,1152)=V.
// ---------------------------------------------------------------------------
__global__ __launch_bounds__(64) void attn_kernel(
    const bf16* __restrict__ qkv, const float* __restrict__ addend,
    bf16* __restrict__ attn_out) {
  const int bid = xcd_swz(blockIdx.x, 12288);   // 12 consecutive bids share a window
  const int b = bid / 12;
  const int h = bid % 12;
  const int w = b & 63;
  const int lane = threadIdx.x;
  const int lr = lane & 15, lg = lane >> 4;
  const float scale = 0.17677669529663687f;  // 32^-0.5

  __shared__ ushort p_lds[64][72];
  __shared__ ushort vT[32][72];

  const size_t base = (size_t)b * 49 * 1152;

  // --- Q, K fragments straight from global (rows >= 49 clamped to 48)
  bf16x8 qf[4], kf[4];
#pragma unroll
  for (int i = 0; i < 4; i++) {
    int rw = i * 16 + lr;
    int row = rw < 49 ? rw : 48;
    qf[i] = *reinterpret_cast<const bf16x8*>(qkv + base + (size_t)row * 1152 + h * 32 + lg * 8);
    kf[i] = *reinterpret_cast<const bf16x8*>(qkv + base + (size_t)row * 1152 + 384 + h * 32 + lg * 8);
  }

  // --- stage V transposed into LDS: vT[d][k] = V[k][d]; pad k>=49 with 0
  if (lane < 49) {
#pragma unroll
    for (int c4 = 0; c4 < 4; c4++) {
      bf16x8 vv = *reinterpret_cast<const bf16x8*>(
          qkv + base + (size_t)lane * 1152 + 768 + h * 32 + c4 * 8);
#pragma unroll
      for (int cc = 0; cc < 8; cc++) vT[c4 * 8 + cc][lane] = (ushort)vv[cc];
    }
  } else {
#pragma unroll
    for (int c = 0; c < 32; c++) vT[c][lane] = 0;
  }

  // --- S = Q @ K^T (64x64 padded), C-layout: row=(lg*4+reg), col=lr per tile
  f32x4 acc[4][4] = {};
#pragma unroll
  for (int i = 0; i < 4; i++)
#pragma unroll
    for (int j = 0; j < 4; j++)
      acc[i][j] = __builtin_amdgcn_mfma_f32_16x16x32_bf16(qf[i], kf[j], acc[i][j], 0, 0, 0);

  // --- softmax in-register (rows distributed: 16 lanes of group lg share rows)
  const float* add_base = addend + (size_t)(w * 12 + h) * 49 * 64;
  float rowscale[4][4];
#pragma unroll
  for (int i = 0; i < 4; i++) {
#pragma unroll
    for (int r = 0; r < 4; r++) {
      int row = i * 16 + lg * 4 + r;
      int rowc = row < 49 ? row : 48;
      float lv[4];
      float mx = -1e38f;
#pragma unroll
      for (int j = 0; j < 4; j++) {
        int col = j * 16 + lr;
        float ad = add_base[rowc * 64 + col];
        lv[j] = acc[i][j][r] * scale + ad;
        mx = fmaxf(mx, lv[j]);
      }
#pragma unroll
      for (int d = 1; d < 16; d <<= 1) mx = fmaxf(mx, __shfl_xor(mx, d, 64));
      float sum = 0.f;
#pragma unroll
      for (int j = 0; j < 4; j++) {
        lv[j] = __expf(lv[j] - mx);
        sum += lv[j];
      }
#pragma unroll
      for (int d = 1; d < 16; d <<= 1) sum += __shfl_xor(sum, d, 64);
      rowscale[i][r] = 1.0f / sum;
#pragma unroll
      for (int j = 0; j < 4; j++) acc[i][j][r] = lv[j];
    }
  }

  // --- write P (unnormalized) to LDS as bf16
#pragma unroll
  for (int i = 0; i < 4; i++)
#pragma unroll
    for (int j = 0; j < 4; j++)
#pragma unroll
      for (int r = 0; r < 4; r++) {
        int row = i * 16 + lg * 4 + r;
        int col = j * 16 + lr;
        p_lds[row][col] = __bfloat16_as_ushort(__float2bfloat16(acc[i][j][r]));
      }
  __syncthreads();

  // --- O = P @ V  (K-dim 64, 2 steps of 32)
  f32x4 acc2[4][2] = {};
#pragma unroll
  for (int ks = 0; ks < 2; ks++) {
    bf16x8 vf[2];
#pragma unroll
    for (int dt = 0; dt < 2; dt++)
      vf[dt] = *reinterpret_cast<const bf16x8*>(&vT[dt * 16 + lr][ks * 32 + lg * 8]);
#pragma unroll
    for (int i = 0; i < 4; i++) {
      bf16x8 pf = *reinterpret_cast<const bf16x8*>(&p_lds[i * 16 + lr][ks * 32 + lg * 8]);
#pragma unroll
      for (int dt = 0; dt < 2; dt++)
        acc2[i][dt] = __builtin_amdgcn_mfma_f32_16x16x32_bf16(pf, vf[dt], acc2[i][dt], 0, 0, 0);
    }
  }

  // --- store attn_out (bf16), normalize by 1/rowsum
#pragma unroll
  for (int i = 0; i < 4; i++)
#pragma unroll
    for (int r = 0; r < 4; r++) {
      int row = i * 16 + lg * 4 + r;
      if (row < 49) {
        float rs = rowscale[i][r];
#pragma unroll
        for (int dt = 0; dt < 2; dt++) {
          int col = h * 32 + dt * 16 + lr;
          attn_out[((size_t)b * 49 + row) * 384 + col] =
              __float2bfloat16(acc2[i][dt][r] * rs);
        }
      }
    }
}

// ---------------------------------------------------------------------------
// launch
// ---------------------------------------------------------------------------
extern "C" void kernel_launch(void* const* d_in, const int* in_sizes, int n_in,
                              void* d_out, int out_size, void* d_ws, size_t ws_size,
                              hipStream_t stream) {
  const float* x      = (const float*)d_in[0];
  const float* mask   = (const float*)d_in[1];
  const int*   posidx = (const int*)d_in[2];
  const float* table  = (const float*)d_in[3];
  const float* w_qkv  = (const float*)d_in[4];
  const float* b_qkv  = (const float*)d_in[5];
  const float* w_proj = (const float*)d_in[6];
  const float* b_proj = (const float*)d_in[7];
  float* out = (float*)d_out;

  char* ws = (char*)d_ws;
  bf16*  xb     = (bf16*)(ws + 0);            // 50176*384   bf16 = 38,535,168 B
  bf16*  wqkvb  = (bf16*)(ws + 38535168);     // 1152*384    bf16 =    884,736 B
  bf16*  wprojb = (bf16*)(ws + 39419904);     // 384*384     bf16 =    294,912 B
  bf16*  qkv    = (bf16*)(ws + 39714816);     // 50176*1152  bf16 = 115,605,504 B
  bf16*  aout   = (bf16*)(ws + 155320320);    // 50176*384   bf16 = 38,535,168 B
  float* addend = (float*)(ws + 193855488);   // 64*12*49*64 f32  =  9,633,792 B

  // conversions (exact grids: sizes all divisible by 1024)
  cvt_f32_bf16<<<18816, 256, 0, stream>>>(x, xb);        // 19,267,584 elems
  cvt_f32_bf16<<<432, 256, 0, stream>>>(w_qkv, wqkvb);   //    442,368 elems
  cvt_f32_bf16<<<144, 256, 0, stream>>>(w_proj, wprojb); //    147,456 elems

  // fused bias+mask addend table
  build_addend<<<9408, 256, 0, stream>>>(mask, posidx, table, addend);

  // qkv = x @ w_qkv^T + b_qkv   (M=50176, N=1152, K=384)
  gemm_bt<true><<<392 * 9, 256, 0, stream>>>(xb, wqkvb, b_qkv, qkv, 50176, 1152, 384, 9, 392 * 9);

  // attention per (window-batch, head)
  attn_kernel<<<12288, 64, 0, stream>>>(qkv, addend, aout);

  // out = attn_out @ w_proj^T + b_proj   (M=50176, N=384, K=384)
  gemm_bt<false><<<392 * 3, 256, 0, stream>>>(aout, wprojb, b_proj, out, 50176, 384, 384, 3, 392 * 3);
}